// Round 1
// baseline (25.789 us; speedup 1.0000x reference)
//
#include <hip/hip_runtime.h>

#define B_  256
#define P_  1152
#define J_  10
#define K_  8
#define D_  16
#define NT  1024

// LDS float layout (total 36468 floats = 145872 bytes < 160 KiB):
//  xs   [1152][9]  x, row-padded to 9 for bank-conflict-free per-lane k reads
//  Wl   [10][16][8]
//  bt   [10][1152] routing logits, transposed (lane<->p reads/writes coalesce)
//  et   [10][1152] exp(b - m), transposed
//  ypart[16][80]   per-wave y partials
//  ysum [80], sj [160], vj [160], zl [80], invS [10], scal [10]

__global__ __launch_bounds__(NT) void caps_kernel(const float* __restrict__ x,
                                                  const float* __restrict__ Wg,
                                                  float* __restrict__ out) {
  extern __shared__ float sm[];
  float* xs    = sm;               // 10368
  float* Wl    = xs + 10368;       // 1280
  float* bt    = Wl + 1280;        // 11520
  float* et    = bt + 11520;       // 11520
  float* ypart = et + 11520;       // 1280
  float* ysum  = ypart + 1280;     // 80
  float* sj    = ysum + 80;        // 160
  float* vj    = sj + 160;         // 160
  float* zl    = vj + 160;         // 80
  float* invS  = zl + 80;          // 10
  float* scal  = invS + 10;        // 10

  const int tid  = threadIdx.x;
  const int w    = tid >> 6;
  const int lane = tid & 63;
  const int b    = blockIdx.x;

  // ---------------- preamble: stage x, W; init b=0, e=1 ----------------
  const float* xb = x + (size_t)b * (P_ * K_);
  for (int i = tid; i < (P_ * K_) / 4; i += NT) {
    float4 v4 = reinterpret_cast<const float4*>(xb)[i];
    int p  = i >> 1;
    int k0 = (i & 1) * 4;
    float* dst = xs + p * 9 + k0;
    dst[0] = v4.x; dst[1] = v4.y; dst[2] = v4.z; dst[3] = v4.w;
  }
  for (int i = tid; i < J_ * D_ * K_; i += NT) Wl[i] = Wg[i];
  for (int i = tid; i < (J_ * P_) / 4; i += NT) {
    reinterpret_cast<float4*>(bt)[i] = make_float4(0.f, 0.f, 0.f, 0.f);
    reinterpret_cast<float4*>(et)[i] = make_float4(1.f, 1.f, 1.f, 1.f);
  }
  if (tid < J_) invS[tid] = 1.0f / (float)P_;
  __syncthreads();

  for (int it = 0; it < 3; ++it) {
    // ---------------- pass S: softmax stats over p (skip iter 0: b==0) ----------------
    if (it > 0) {
      if (w < J_) {
        const float* bj = bt + w * P_;
        float mx = -3.0e38f;
        #pragma unroll
        for (int c = 0; c < 18; ++c) mx = fmaxf(mx, bj[c * 64 + lane]);
        #pragma unroll
        for (int s = 1; s < 64; s <<= 1) mx = fmaxf(mx, __shfl_xor(mx, s));
        float sum = 0.f;
        #pragma unroll
        for (int c = 0; c < 18; ++c) {
          float e = __expf(bj[c * 64 + lane] - mx);
          et[w * P_ + c * 64 + lane] = e;
          sum += e;
        }
        #pragma unroll
        for (int s = 1; s < 64; s <<= 1) sum += __shfl_xor(sum, s);
        if (lane == 0) invS[w] = 1.0f / sum;
      }
      __syncthreads();
    }

    // ---------------- pass Y: y[j][k] = sum_p e[p][j] * x[p][k] ----------------
    {
      float acc[J_];
      #pragma unroll
      for (int j = 0; j < J_; ++j) acc[j] = 0.f;
      const int psub = lane >> 3, k = lane & 7;
      for (int c = w; c < 144; c += 16) {           // 9 chunks of 8 p per wave
        const int p = c * 8 + psub;
        const float xv = xs[p * 9 + k];
        const float* ep = et + p;
        #pragma unroll
        for (int j = 0; j < J_; ++j) acc[j] = fmaf(ep[j * P_], xv, acc[j]);
      }
      #pragma unroll
      for (int j = 0; j < J_; ++j) {                // reduce over psub (lane bits 3..5)
        acc[j] += __shfl_xor(acc[j], 8);
        acc[j] += __shfl_xor(acc[j], 16);
        acc[j] += __shfl_xor(acc[j], 32);
      }
      if (lane < 8) {
        #pragma unroll
        for (int j = 0; j < J_; ++j) ypart[w * 80 + j * 8 + lane] = acc[j];
      }
    }
    __syncthreads();

    // ---------------- combine partials, s = W @ (invS * y), squash, v, z ----------------
    if (tid < 80) {
      float s = 0.f;
      #pragma unroll
      for (int w2 = 0; w2 < 16; ++w2) s += ypart[w2 * 80 + tid];
      ysum[tid] = s;
    }
    __syncthreads();
    if (tid < 160) {
      const int j = tid >> 4, d = tid & 15;
      float s = 0.f;
      #pragma unroll
      for (int k = 0; k < 8; ++k) s = fmaf(Wl[(j * 16 + d) * 8 + k], ysum[j * 8 + k], s);
      s *= invS[j];
      sj[tid] = s;
    }
    __syncthreads();
    if (tid < J_) {
      float sq = 0.f;
      #pragma unroll
      for (int d = 0; d < 16; ++d) { float t = sj[tid * 16 + d]; sq = fmaf(t, t, sq); }
      scal[tid] = sq / ((1.0f + sq) * sqrtf(sq + 1e-9f));
    }
    __syncthreads();
    if (tid < 160) {
      float vv = sj[tid] * scal[tid >> 4];
      if (it == 2) out[b * 160 + tid] = vv;         // final output, coalesced
      else         vj[tid] = vv;
    }
    __syncthreads();

    if (it < 2) {
      if (tid < 80) {                                // z[j][k] = sum_d W[j][d][k] * v[j][d]
        const int j = tid >> 3, k = tid & 7;
        float z = 0.f;
        #pragma unroll
        for (int d = 0; d < 16; ++d) z = fmaf(Wl[(j * 16 + d) * 8 + k], vj[j * 16 + d], z);
        zl[tid] = z;
      }
      __syncthreads();
      // ---------------- pass B: b[j][p] += x[p] . z[j] ----------------
      for (int c = w; c < 18; c += 16) {             // chunks of 64 p
        const int p = c * 64 + lane;
        float xv[8];
        #pragma unroll
        for (int k = 0; k < 8; ++k) xv[k] = xs[p * 9 + k];
        #pragma unroll
        for (int j = 0; j < J_; ++j) {
          const float4 z0 = reinterpret_cast<const float4*>(zl + j * 8)[0];
          const float4 z1 = reinterpret_cast<const float4*>(zl + j * 8)[1];
          float dlt = bt[j * P_ + p];
          dlt = fmaf(xv[0], z0.x, dlt);
          dlt = fmaf(xv[1], z0.y, dlt);
          dlt = fmaf(xv[2], z0.z, dlt);
          dlt = fmaf(xv[3], z0.w, dlt);
          dlt = fmaf(xv[4], z1.x, dlt);
          dlt = fmaf(xv[5], z1.y, dlt);
          dlt = fmaf(xv[6], z1.z, dlt);
          dlt = fmaf(xv[7], z1.w, dlt);
          bt[j * P_ + p] = dlt;
        }
      }
      __syncthreads();
    }
  }
}

extern "C" void kernel_launch(void* const* d_in, const int* in_sizes, int n_in,
                              void* d_out, int out_size, void* d_ws, size_t ws_size,
                              hipStream_t stream) {
  (void)in_sizes; (void)n_in; (void)out_size; (void)d_ws; (void)ws_size;
  const float* x = (const float*)d_in[0];
  const float* W = (const float*)d_in[1];
  float* out = (float*)d_out;

  const size_t smem = 36468u * sizeof(float);  // 145872 B
  (void)hipFuncSetAttribute(reinterpret_cast<const void*>(caps_kernel),
                            hipFuncAttributeMaxDynamicSharedMemorySize, (int)smem);
  caps_kernel<<<B_, NT, smem, stream>>>(x, W, out);
}

// Round 2
// 24.588 us; speedup vs baseline: 1.0488x; 1.0488x over previous
//
#include <hip/hip_runtime.h>

#define B_  256
#define P_  1152
#define J_  10
#define K_  8
#define D_  16
#define NT  1024
#define NW  16

// LDS float layout (38522 floats = 154088 B < 160 KiB):
//  xs   [1152][9]   @0      x, stride-9 rows (conflict-free per-(p,k) and per-p-row b32)
//  Wl   [10][16][9] @10368  W, stride-9 padded
//  bt   [10][1152]  @11808  routing logits, transposed (lane<->p conflict-free)
//  et   [1152][12]  @23328  exp(b), XOR-swizzled: idx=(p*12+j)^(((p>>3)&3)<<2)
//                           -> float4/float4/float2 broadcast reads in pass Y,
//                              ~2-way scatter writes in pass S
//  ypart[16][80]    @37152  per-wave y partials
//  zl   [80]        @38432, invS[10] @38512

__global__ __launch_bounds__(NT) void caps_kernel(const float* __restrict__ x,
                                                  const float* __restrict__ Wg,
                                                  float* __restrict__ out) {
  extern __shared__ float sm[];
  float* xs    = sm;
  float* Wl    = sm + 10368;
  float* bt    = sm + 11808;
  float* et    = sm + 23328;
  float* ypart = sm + 37152;
  float* zl    = sm + 38432;
  float* invS  = sm + 38512;

  const int tid  = threadIdx.x;
  const int w    = tid >> 6;
  const int lane = tid & 63;
  const int b    = blockIdx.x;
  const int psub = lane >> 3, kk = lane & 7;

  // ---------------- preamble: stage x, W; invS = 1/P ----------------
  const float* xb = x + (size_t)b * (P_ * K_);
  for (int i = tid; i < (P_ * K_) / 4; i += NT) {
    float4 v4 = reinterpret_cast<const float4*>(xb)[i];
    int p = i >> 1, k0 = (i & 1) * 4;
    float* dst = xs + p * 9 + k0;
    dst[0] = v4.x; dst[1] = v4.y; dst[2] = v4.z; dst[3] = v4.w;
  }
  for (int i = tid; i < J_ * D_ * K_; i += NT) Wl[(i >> 3) * 9 + (i & 7)] = Wg[i];
  if (tid < J_) invS[tid] = 1.0f / (float)P_;
  __syncthreads();

  for (int it = 0; it < 3; ++it) {
    // ---- pass S: e = exp(b) (no max; |b| bounded ~30), per-j sum ----
    if (it > 0) {
      if (w < J_) {
        float sum = 0.f;
        #pragma unroll
        for (int c = 0; c < 18; ++c) {
          const int p = c * 64 + lane;
          const float e = __expf(bt[w * P_ + p]);
          et[(p * 12 + w) ^ (((p >> 3) & 3) << 2)] = e;
          sum += e;
        }
        #pragma unroll
        for (int s = 1; s < 64; s <<= 1) sum += __shfl_xor(sum, s);
        if (lane == 0) invS[w] = 1.0f / sum;
      }
      __syncthreads();
    }

    // ---- pass Y: y[j][k] = sum_p e[p][j] x[p][k] ----
    {
      float acc[J_];
      if (it == 0) {                       // e == 1: plain column sum
        float a0 = 0.f;
        for (int c = w; c < 144; c += NW) a0 += xs[(c * 8 + psub) * 9 + kk];
        #pragma unroll
        for (int j = 0; j < J_; ++j) acc[j] = a0;
      } else {
        #pragma unroll
        for (int j = 0; j < J_; ++j) acc[j] = 0.f;
        for (int c = w; c < 144; c += NW) {
          const int p  = c * 8 + psub;
          const float xv = xs[p * 9 + kk];
          const int rb = p * 12, X = ((p >> 3) & 3) << 2;
          const float4 ea = *reinterpret_cast<const float4*>(et + ((rb)     ^ X));
          const float4 eb = *reinterpret_cast<const float4*>(et + ((rb + 4) ^ X));
          const float2 ec = *reinterpret_cast<const float2*>(et + ((rb + 8) ^ X));
          acc[0] = fmaf(ea.x, xv, acc[0]); acc[1] = fmaf(ea.y, xv, acc[1]);
          acc[2] = fmaf(ea.z, xv, acc[2]); acc[3] = fmaf(ea.w, xv, acc[3]);
          acc[4] = fmaf(eb.x, xv, acc[4]); acc[5] = fmaf(eb.y, xv, acc[5]);
          acc[6] = fmaf(eb.z, xv, acc[6]); acc[7] = fmaf(eb.w, xv, acc[7]);
          acc[8] = fmaf(ec.x, xv, acc[8]); acc[9] = fmaf(ec.y, xv, acc[9]);
        }
      }
      #pragma unroll
      for (int j = 0; j < J_; ++j) {       // reduce over psub (lane bits 3..5)
        acc[j] += __shfl_xor(acc[j], 8);
        acc[j] += __shfl_xor(acc[j], 16);
        acc[j] += __shfl_xor(acc[j], 32);
      }
      if (lane < 8) {
        #pragma unroll
        for (int j = 0; j < J_; ++j) ypart[w * 80 + j * 8 + lane] = acc[j];
      }
    }
    __syncthreads();

    // ---- mega stage (tid<160): ysum -> s -> squash -> v (-> out | z) ----
    if (tid < 160) {
      const int j = tid >> 4, d = tid & 15;
      float ys = 0.f;
      if (d < 8) {
        #pragma unroll
        for (int w2 = 0; w2 < NW; ++w2) ys += ypart[w2 * 80 + j * 8 + d];
      }
      float wk[8];
      #pragma unroll
      for (int k = 0; k < 8; ++k) wk[k] = Wl[(j * 16 + d) * 9 + k];
      float s = 0.f;
      #pragma unroll
      for (int k = 0; k < 8; ++k)
        s = fmaf(wk[k], __shfl(ys, (j & 3) * 16 + k), s);
      s *= invS[j];
      float sq = s * s;                    // squash via 16-lane group reduce
      sq += __shfl_xor(sq, 1); sq += __shfl_xor(sq, 2);
      sq += __shfl_xor(sq, 4); sq += __shfl_xor(sq, 8);
      const float scal = sq / ((1.0f + sq) * sqrtf(sq + 1e-9f));
      const float v = s * scal;
      if (it == 2) {
        out[b * 160 + tid] = v;
      } else {                             // z[j][k] = sum_d W[j][d][k] v_d
        float zmine = 0.f;
        #pragma unroll
        for (int k = 0; k < 8; ++k) {
          float t = wk[k] * v;
          t += __shfl_xor(t, 1); t += __shfl_xor(t, 2);
          t += __shfl_xor(t, 4); t += __shfl_xor(t, 8);
          if (d == k) zmine = t;
        }
        if (d < 8) zl[j * 8 + d] = zmine;
      }
    }
    if (it == 2) break;
    __syncthreads();

    // ---- pass B: b[j][p] (+)= x[p] . z[j] ----
    {
      float4 zr[20];
      #pragma unroll
      for (int jj = 0; jj < J_; ++jj) {
        zr[2 * jj]     = *reinterpret_cast<const float4*>(zl + jj * 8);
        zr[2 * jj + 1] = *reinterpret_cast<const float4*>(zl + jj * 8 + 4);
      }
      for (int c = w; c < 18; c += NW) {
        const int p = c * 64 + lane;
        float xv[8];
        #pragma unroll
        for (int k = 0; k < 8; ++k) xv[k] = xs[p * 9 + k];
        #pragma unroll
        for (int j = 0; j < J_; ++j) {
          const float4 z0 = zr[2 * j], z1 = zr[2 * j + 1];
          float dlt = xv[0] * z0.x;
          dlt = fmaf(xv[1], z0.y, dlt);
          dlt = fmaf(xv[2], z0.z, dlt);
          dlt = fmaf(xv[3], z0.w, dlt);
          dlt = fmaf(xv[4], z1.x, dlt);
          dlt = fmaf(xv[5], z1.y, dlt);
          dlt = fmaf(xv[6], z1.z, dlt);
          dlt = fmaf(xv[7], z1.w, dlt);
          bt[j * P_ + p] = (it == 0) ? dlt : (bt[j * P_ + p] + dlt);
        }
      }
    }
    __syncthreads();
  }
}

extern "C" void kernel_launch(void* const* d_in, const int* in_sizes, int n_in,
                              void* d_out, int out_size, void* d_ws, size_t ws_size,
                              hipStream_t stream) {
  (void)in_sizes; (void)n_in; (void)out_size; (void)d_ws; (void)ws_size;
  const float* x = (const float*)d_in[0];
  const float* W = (const float*)d_in[1];
  float* out = (float*)d_out;

  const size_t smem = 38522u * sizeof(float);  // 154088 B
  (void)hipFuncSetAttribute(reinterpret_cast<const void*>(caps_kernel),
                            hipFuncAttributeMaxDynamicSharedMemorySize, (int)smem);
  caps_kernel<<<B_, NT, smem, stream>>>(x, W, out);
}

// Round 3
// 23.899 us; speedup vs baseline: 1.0791x; 1.0288x over previous
//
#include <hip/hip_runtime.h>

#define B_  256
#define P_  1152
#define J_  10
#define NT  1024
#define NW  16
#define LOG2E 1.44269504088896340736f

// Rank-8 routing: b[p,j] == x[p] . Z[j] with Z = sum of per-iter z, so the
// [10][1152] logit array is never materialized. Per iteration:
//   S: e[p][j] = exp2(x[p].Z[j])  (Z pre-scaled by log2e)  -> et (swizzled)
//   Y: y[j][k] = sum_p e[p][j] x[p][k]; S[j] = sum_p e[p][j] via mask-fma
//   mega: s = W.y / S -> squash -> v -> z -> Z += z*log2e
//
// LDS floats (27152 = 108608 B):
//  xs    [1152][9] @0      stride-9 rows (2-way-max bank aliasing everywhere)
//  Wl    [10][16][9] @10368
//  et    [1152][12] @11808 XOR-swizzled: idx=(p*12+j)^(((p>>3)&3)<<2)
//  ypart [16][80]  @25632
//  spart [16][10]  @26912
//  Zacc  [80]      @27072

__global__ __launch_bounds__(NT, 4) void caps_kernel(const float* __restrict__ x,
                                                     const float* __restrict__ Wg,
                                                     float* __restrict__ out) {
  extern __shared__ float sm[];
  float* xs    = sm;
  float* Wl    = sm + 10368;
  float* et    = sm + 11808;
  float* ypart = sm + 25632;
  float* spart = sm + 26912;
  float* Zacc  = sm + 27072;

  const int tid  = threadIdx.x;
  const int w    = tid >> 6;
  const int lane = tid & 63;
  const int b    = blockIdx.x;
  const int psub = lane >> 3, kk = lane & 7;

  // ---------------- preamble: stage x, W ----------------
  const float* xb = x + (size_t)b * (P_ * 8);
  for (int i = tid; i < (P_ * 8) / 4; i += NT) {
    float4 v4 = reinterpret_cast<const float4*>(xb)[i];
    int p = i >> 1, k0 = (i & 1) * 4;
    float* dst = xs + p * 9 + k0;
    dst[0] = v4.x; dst[1] = v4.y; dst[2] = v4.z; dst[3] = v4.w;
  }
  for (int i = tid; i < J_ * 16 * 8; i += NT) Wl[(i >> 3) * 9 + (i & 7)] = Wg[i];
  __syncthreads();

  for (int it = 0; it < 3; ++it) {
    // ---- S-pass: e = exp2(x . Zacc), swizzled scatter to et ----
    if (it > 0) {
      for (int c = w; c < 18; c += NW) {
        const int p = c * 64 + lane;
        float xv[8];
        #pragma unroll
        for (int k = 0; k < 8; ++k) xv[k] = xs[p * 9 + k];
        float e10[J_];
        #pragma unroll
        for (int j = 0; j < J_; ++j) {
          const float4 z0 = *reinterpret_cast<const float4*>(Zacc + j * 8);
          const float4 z1 = *reinterpret_cast<const float4*>(Zacc + j * 8 + 4);
          float bb = xv[0] * z0.x;
          bb = fmaf(xv[1], z0.y, bb);
          bb = fmaf(xv[2], z0.z, bb);
          bb = fmaf(xv[3], z0.w, bb);
          bb = fmaf(xv[4], z1.x, bb);
          bb = fmaf(xv[5], z1.y, bb);
          bb = fmaf(xv[6], z1.z, bb);
          bb = fmaf(xv[7], z1.w, bb);
          e10[j] = exp2f(bb);
        }
        const int rb = p * 12, X = ((p >> 3) & 3) << 2;
        *reinterpret_cast<float4*>(et + ((rb)     ^ X)) = make_float4(e10[0], e10[1], e10[2], e10[3]);
        *reinterpret_cast<float4*>(et + ((rb + 4) ^ X)) = make_float4(e10[4], e10[5], e10[6], e10[7]);
        *reinterpret_cast<float2*>(et + ((rb + 8) ^ X)) = make_float2(e10[8], e10[9]);
      }
      __syncthreads();
    }

    // ---- Y-pass: y[j][k] = sum_p e x ; S[j] via mask-fma on kk==0 lanes ----
    {
      float acc[J_], accs[J_];
      if (it == 0) {                      // e == 1: plain column sum
        float a0 = 0.f;
        #pragma unroll 3
        for (int c = w; c < 144; c += NW) a0 += xs[(c * 8 + psub) * 9 + kk];
        #pragma unroll
        for (int j = 0; j < J_; ++j) acc[j] = a0;
      } else {
        const float msk = (kk == 0) ? 1.0f : 0.0f;
        #pragma unroll
        for (int j = 0; j < J_; ++j) { acc[j] = 0.f; accs[j] = 0.f; }
        #pragma unroll 3
        for (int c = w; c < 144; c += NW) {
          const int p  = c * 8 + psub;
          const float xv = xs[p * 9 + kk];
          const int rb = p * 12, X = ((p >> 3) & 3) << 2;
          const float4 ea = *reinterpret_cast<const float4*>(et + ((rb)     ^ X));
          const float4 eb = *reinterpret_cast<const float4*>(et + ((rb + 4) ^ X));
          const float2 ec = *reinterpret_cast<const float2*>(et + ((rb + 8) ^ X));
          acc[0] = fmaf(ea.x, xv, acc[0]); accs[0] = fmaf(msk, ea.x, accs[0]);
          acc[1] = fmaf(ea.y, xv, acc[1]); accs[1] = fmaf(msk, ea.y, accs[1]);
          acc[2] = fmaf(ea.z, xv, acc[2]); accs[2] = fmaf(msk, ea.z, accs[2]);
          acc[3] = fmaf(ea.w, xv, acc[3]); accs[3] = fmaf(msk, ea.w, accs[3]);
          acc[4] = fmaf(eb.x, xv, acc[4]); accs[4] = fmaf(msk, eb.x, accs[4]);
          acc[5] = fmaf(eb.y, xv, acc[5]); accs[5] = fmaf(msk, eb.y, accs[5]);
          acc[6] = fmaf(eb.z, xv, acc[6]); accs[6] = fmaf(msk, eb.z, accs[6]);
          acc[7] = fmaf(eb.w, xv, acc[7]); accs[7] = fmaf(msk, eb.w, accs[7]);
          acc[8] = fmaf(ec.x, xv, acc[8]); accs[8] = fmaf(msk, ec.x, accs[8]);
          acc[9] = fmaf(ec.y, xv, acc[9]); accs[9] = fmaf(msk, ec.y, accs[9]);
        }
      }
      #pragma unroll
      for (int j = 0; j < J_; ++j) {      // reduce over psub (lane bits 3..5)
        acc[j] += __shfl_xor(acc[j], 8);
        acc[j] += __shfl_xor(acc[j], 16);
        acc[j] += __shfl_xor(acc[j], 32);
      }
      if (it > 0) {
        #pragma unroll
        for (int j = 0; j < J_; ++j) {
          accs[j] += __shfl_xor(accs[j], 8);
          accs[j] += __shfl_xor(accs[j], 16);
          accs[j] += __shfl_xor(accs[j], 32);
        }
        if (lane == 0) {
          #pragma unroll
          for (int j = 0; j < J_; ++j) spart[w * 10 + j] = accs[j];
        }
      }
      if (lane < 8) {
        #pragma unroll
        for (int j = 0; j < J_; ++j) ypart[w * 80 + j * 8 + lane] = acc[j];
      }
    }
    __syncthreads();

    // ---- mega (tid<160): combine -> s -> squash -> v (-> out | Z update) ----
    if (tid < 160) {
      const int j = tid >> 4, d = tid & 15;
      float ys = 0.f;
      if (d < 8) {
        #pragma unroll
        for (int w2 = 0; w2 < NW; ++w2) ys += ypart[w2 * 80 + j * 8 + d];
      }
      float Ssum;
      if (it == 0) {
        Ssum = (float)P_;
      } else {
        float sp = spart[d * 10 + j];      // d indexes the wave partial
        sp += __shfl_xor(sp, 1); sp += __shfl_xor(sp, 2);
        sp += __shfl_xor(sp, 4); sp += __shfl_xor(sp, 8);
        Ssum = sp;
      }
      float wk[8];
      #pragma unroll
      for (int k = 0; k < 8; ++k) wk[k] = Wl[(j * 16 + d) * 9 + k];
      float s = 0.f;
      #pragma unroll
      for (int k = 0; k < 8; ++k)
        s = fmaf(wk[k], __shfl(ys, (j & 3) * 16 + k), s);
      s /= Ssum;
      float sq = s * s;                    // squash via 16-lane group reduce
      sq += __shfl_xor(sq, 1); sq += __shfl_xor(sq, 2);
      sq += __shfl_xor(sq, 4); sq += __shfl_xor(sq, 8);
      const float scal = sq / ((1.0f + sq) * sqrtf(sq + 1e-9f));
      const float v = s * scal;
      if (it == 2) {
        out[b * 160 + tid] = v;
      } else {                             // z[j][k] = sum_d W[j][d][k] v_d
        float zmine = 0.f;
        #pragma unroll
        for (int k = 0; k < 8; ++k) {
          float t = wk[k] * v;
          t += __shfl_xor(t, 1); t += __shfl_xor(t, 2);
          t += __shfl_xor(t, 4); t += __shfl_xor(t, 8);
          if (d == k) zmine = t;
        }
        if (d < 8) {
          const float zz = zmine * LOG2E;  // pre-scale so S-pass uses exp2
          Zacc[j * 8 + d] = (it == 0) ? zz : (Zacc[j * 8 + d] + zz);
        }
      }
    }
    if (it < 2) __syncthreads();
  }
}

extern "C" void kernel_launch(void* const* d_in, const int* in_sizes, int n_in,
                              void* d_out, int out_size, void* d_ws, size_t ws_size,
                              hipStream_t stream) {
  (void)in_sizes; (void)n_in; (void)out_size; (void)d_ws; (void)ws_size;
  const float* x = (const float*)d_in[0];
  const float* W = (const float*)d_in[1];
  float* out = (float*)d_out;

  const size_t smem = 27152u * sizeof(float);  // 108608 B
  (void)hipFuncSetAttribute(reinterpret_cast<const void*>(caps_kernel),
                            hipFuncAttributeMaxDynamicSharedMemorySize, (int)smem);
  caps_kernel<<<B_, NT, smem, stream>>>(x, W, out);
}